// Round 3
// baseline (205.635 us; speedup 1.0000x reference)
//
#include <hip/hip_runtime.h>
#include <math.h>

#define DIM 8
constexpr int B = 8;
constexpr int S = 1024;

typedef float floatx4 __attribute__((ext_vector_type(4)));

// ---------------------------------------------------------------------------
// Kernel 1: q/k projection + grade-wise normalization.
// One thread per (b,s) token. 8192 threads total.
// ---------------------------------------------------------------------------
__global__ void __launch_bounds__(256) prep_qk_kernel(
    const float* __restrict__ x,       // (B,S,8)
    const float* __restrict__ qw,      // (8,8) row = d, col = i
    const float* __restrict__ qb,      // (1,)
    const float* __restrict__ kw,      // (8,8)
    const float* __restrict__ kb,      // (1,)
    const float* __restrict__ an,      // (3000,4)
    float* __restrict__ qn,            // (B,S,8)
    float* __restrict__ kn)            // (B,S,8)
{
    int idx = blockIdx.x * blockDim.x + threadIdx.x;   // b*S + s
    if (idx >= B * S) return;
    int s = idx & (S - 1);

    const float4* xp = reinterpret_cast<const float4*>(x + (size_t)idx * 8);
    float4 xa = xp[0], xb = xp[1];
    float xv[8] = {xa.x, xa.y, xa.z, xa.w, xb.x, xb.y, xb.z, xb.w};

    float sa[4];
#pragma unroll
    for (int g = 0; g < 4; ++g) {
        float a = an[s * 4 + g];
        sa[g] = 1.0f / (1.0f + expf(-a));
    }

    float qv[8], kv[8];
#pragma unroll
    for (int i = 0; i < 8; ++i) {
        float accq = (i == 0) ? qb[0] : 0.0f;
        float acck = (i == 0) ? kb[0] : 0.0f;
#pragma unroll
        for (int d = 0; d < 8; ++d) {
            accq += xv[d] * qw[d * 8 + i];
            acck += xv[d] * kw[d * 8 + i];
        }
        qv[i] = accq;
        kv[i] = acck;
    }

    {
        float n0 = sqrtf(qv[0] * qv[0]);
        float n1 = sqrtf(qv[1] * qv[1] + qv[2] * qv[2] + qv[3] * qv[3]);
        float n2 = sqrtf(qv[4] * qv[4] + qv[5] * qv[5] + qv[6] * qv[6]);
        float n3 = sqrtf(qv[7] * qv[7]);
        float d0 = sa[0] * (n0 - 1.0f) + 1.0f + 1e-6f;
        float d1 = sa[1] * (n1 - 1.0f) + 1.0f + 1e-6f;
        float d2 = sa[2] * (n2 - 1.0f) + 1.0f + 1e-6f;
        float d3 = sa[3] * (n3 - 1.0f) + 1.0f + 1e-6f;
        qv[0] /= d0;
        qv[1] /= d1; qv[2] /= d1; qv[3] /= d1;
        qv[4] /= d2; qv[5] /= d2; qv[6] /= d2;
        qv[7] /= d3;
    }
    {
        float n0 = sqrtf(kv[0] * kv[0]);
        float n1 = sqrtf(kv[1] * kv[1] + kv[2] * kv[2] + kv[3] * kv[3]);
        float n2 = sqrtf(kv[4] * kv[4] + kv[5] * kv[5] + kv[6] * kv[6]);
        float n3 = sqrtf(kv[7] * kv[7]);
        float d0 = sa[0] * (n0 - 1.0f) + 1.0f + 1e-6f;
        float d1 = sa[1] * (n1 - 1.0f) + 1.0f + 1e-6f;
        float d2 = sa[2] * (n2 - 1.0f) + 1.0f + 1e-6f;
        float d3 = sa[3] * (n3 - 1.0f) + 1.0f + 1e-6f;
        kv[0] /= d0;
        kv[1] /= d1; kv[2] /= d1; kv[3] /= d1;
        kv[4] /= d2; kv[5] /= d2; kv[6] /= d2;
        kv[7] /= d3;
    }

    float4* qp = reinterpret_cast<float4*>(qn + (size_t)idx * 8);
    qp[0] = make_float4(qv[0], qv[1], qv[2], qv[3]);
    qp[1] = make_float4(qv[4], qv[5], qv[6], qv[7]);
    float4* kp = reinterpret_cast<float4*>(kn + (size_t)idx * 8);
    kp[0] = make_float4(kv[0], kv[1], kv[2], kv[3]);
    kp[1] = make_float4(kv[4], kv[5], kv[6], kv[7]);
}

// ---------------------------------------------------------------------------
// Kernel 2: pairwise geometric product, 2 t-values per thread.
// Each lane owns a contiguous 64 B output line; nontemporal dwordx4 stores.
// grid = (S/512, S, B), block = 256.
// ---------------------------------------------------------------------------
__device__ __forceinline__ void geom_product(
    float q0, float q1, float q2, float q3, float q4, float q5, float q6, float q7,
    const float* __restrict__ kptr, float* o)
{
    const float4* kp = reinterpret_cast<const float4*>(kptr);
    float4 ka = kp[0], kb4 = kp[1];
    float k0 = ka.x, k1 = ka.y, k2 = ka.z, k3 = ka.w;
    float k4 = kb4.x, k5 = kb4.y, k6 = kb4.z, k7 = kb4.w;

    o[0] = q0*k0 + q1*k1 + q2*k2 + q3*k3 - q4*k4 - q5*k5 - q6*k6 - q7*k7;
    o[1] = q0*k1 + q1*k0 - q2*k4 - q3*k5 + q4*k2 + q5*k3 - q6*k7 - q7*k6;
    o[2] = q0*k2 + q1*k4 + q2*k0 - q3*k6 - q4*k1 + q5*k7 + q6*k3 + q7*k5;
    o[3] = q0*k3 + q1*k5 + q2*k6 + q3*k0 - q4*k7 - q5*k1 - q6*k2 - q7*k4;
    o[4] = q0*k4 + q1*k2 - q2*k1 + q3*k7 + q4*k0 - q5*k6 + q6*k5 + q7*k3;
    o[5] = q0*k5 + q1*k3 - q2*k7 - q3*k1 + q4*k6 + q5*k0 - q6*k4 - q7*k2;
    o[6] = q0*k6 + q1*k7 + q2*k3 - q3*k2 - q4*k5 + q5*k4 + q6*k0 + q7*k1;
    o[7] = q0*k7 + q1*k6 - q2*k5 + q3*k4 + q4*k3 - q5*k2 + q6*k1 + q7*k0;
}

__global__ void __launch_bounds__(256) geomprod_kernel(
    const float* __restrict__ qn,      // (B,S,8)
    const float* __restrict__ kn,      // (B,S,8)
    float* __restrict__ out)           // (B,S,S,8)
{
    int t = (blockIdx.x * 256 + threadIdx.x) * 2;   // even t; this thread does t, t+1
    int s = blockIdx.y;
    int b = blockIdx.z;

    const float4* qp = reinterpret_cast<const float4*>(qn + ((size_t)b * S + s) * 8);
    float4 qa = qp[0], qb4 = qp[1];
    float q0 = qa.x, q1 = qa.y, q2 = qa.z, q3 = qa.w;
    float q4 = qb4.x, q5 = qb4.y, q6 = qb4.z, q7 = qb4.w;

    const float* kbase = kn + ((size_t)b * S + t) * 8;
    float oA[8], oB[8];
    geom_product(q0, q1, q2, q3, q4, q5, q6, q7, kbase, oA);
    geom_product(q0, q1, q2, q3, q4, q5, q6, q7, kbase + 8, oB);

    float* obase = out + (((size_t)b * S + s) * S + t) * 8;
    floatx4* op = reinterpret_cast<floatx4*>(obase);
    floatx4 vA0 = {oA[0], oA[1], oA[2], oA[3]};
    floatx4 vA1 = {oA[4], oA[5], oA[6], oA[7]};
    floatx4 vB0 = {oB[0], oB[1], oB[2], oB[3]};
    floatx4 vB1 = {oB[4], oB[5], oB[6], oB[7]};
    __builtin_nontemporal_store(vA0, op + 0);
    __builtin_nontemporal_store(vA1, op + 1);
    __builtin_nontemporal_store(vB0, op + 2);
    __builtin_nontemporal_store(vB1, op + 3);
}

extern "C" void kernel_launch(void* const* d_in, const int* in_sizes, int n_in,
                              void* d_out, int out_size, void* d_ws, size_t ws_size,
                              hipStream_t stream) {
    const float* x  = (const float*)d_in[0];
    const float* qw = (const float*)d_in[1];
    const float* qb = (const float*)d_in[2];
    const float* kw = (const float*)d_in[3];
    const float* kb = (const float*)d_in[4];
    const float* an = (const float*)d_in[5];
    float* out = (float*)d_out;

    float* qn = (float*)d_ws;                       // B*S*8 floats = 256 KB
    float* kn = qn + (size_t)B * S * 8;             // next 256 KB

    int prep_threads = B * S;                        // 8192
    prep_qk_kernel<<<(prep_threads + 255) / 256, 256, 0, stream>>>(
        x, qw, qb, kw, kb, an, qn, kn);

    dim3 grid(S / 512, S, B);                        // 2 t per thread
    geomprod_kernel<<<grid, 256, 0, stream>>>(qn, kn, out);
}

// Round 4
// 103.988 us; speedup vs baseline: 1.9775x; 1.9775x over previous
//
#include <hip/hip_runtime.h>
#include <math.h>

#define DIM 8
constexpr int B = 8;
constexpr int S = 1024;

// ---------------------------------------------------------------------------
// Kernel 1: q/k projection + grade-wise normalization.
// One thread per (b,s) token. 8192 threads total.
// ---------------------------------------------------------------------------
__global__ void __launch_bounds__(256) prep_qk_kernel(
    const float* __restrict__ x,       // (B,S,8)
    const float* __restrict__ qw,      // (8,8) row = d, col = i
    const float* __restrict__ qb,      // (1,)
    const float* __restrict__ kw,      // (8,8)
    const float* __restrict__ kb,      // (1,)
    const float* __restrict__ an,      // (3000,4)
    float* __restrict__ qn,            // (B,S,8)
    float* __restrict__ kn)            // (B,S,8)
{
    int idx = blockIdx.x * blockDim.x + threadIdx.x;   // b*S + s
    if (idx >= B * S) return;
    int s = idx & (S - 1);

    const float4* xp = reinterpret_cast<const float4*>(x + (size_t)idx * 8);
    float4 xa = xp[0], xb = xp[1];
    float xv[8] = {xa.x, xa.y, xa.z, xa.w, xb.x, xb.y, xb.z, xb.w};

    float sa[4];
#pragma unroll
    for (int g = 0; g < 4; ++g) {
        float a = an[s * 4 + g];
        sa[g] = 1.0f / (1.0f + expf(-a));
    }

    float qv[8], kv[8];
#pragma unroll
    for (int i = 0; i < 8; ++i) {
        float accq = (i == 0) ? qb[0] : 0.0f;
        float acck = (i == 0) ? kb[0] : 0.0f;
#pragma unroll
        for (int d = 0; d < 8; ++d) {
            accq += xv[d] * qw[d * 8 + i];
            acck += xv[d] * kw[d * 8 + i];
        }
        qv[i] = accq;
        kv[i] = acck;
    }

    {
        float n0 = sqrtf(qv[0] * qv[0]);
        float n1 = sqrtf(qv[1] * qv[1] + qv[2] * qv[2] + qv[3] * qv[3]);
        float n2 = sqrtf(qv[4] * qv[4] + qv[5] * qv[5] + qv[6] * qv[6]);
        float n3 = sqrtf(qv[7] * qv[7]);
        float d0 = sa[0] * (n0 - 1.0f) + 1.0f + 1e-6f;
        float d1 = sa[1] * (n1 - 1.0f) + 1.0f + 1e-6f;
        float d2 = sa[2] * (n2 - 1.0f) + 1.0f + 1e-6f;
        float d3 = sa[3] * (n3 - 1.0f) + 1.0f + 1e-6f;
        qv[0] /= d0;
        qv[1] /= d1; qv[2] /= d1; qv[3] /= d1;
        qv[4] /= d2; qv[5] /= d2; qv[6] /= d2;
        qv[7] /= d3;
    }
    {
        float n0 = sqrtf(kv[0] * kv[0]);
        float n1 = sqrtf(kv[1] * kv[1] + kv[2] * kv[2] + kv[3] * kv[3]);
        float n2 = sqrtf(kv[4] * kv[4] + kv[5] * kv[5] + kv[6] * kv[6]);
        float n3 = sqrtf(kv[7] * kv[7]);
        float d0 = sa[0] * (n0 - 1.0f) + 1.0f + 1e-6f;
        float d1 = sa[1] * (n1 - 1.0f) + 1.0f + 1e-6f;
        float d2 = sa[2] * (n2 - 1.0f) + 1.0f + 1e-6f;
        float d3 = sa[3] * (n3 - 1.0f) + 1.0f + 1e-6f;
        kv[0] /= d0;
        kv[1] /= d1; kv[2] /= d1; kv[3] /= d1;
        kv[4] /= d2; kv[5] /= d2; kv[6] /= d2;
        kv[7] /= d3;
    }

    float4* qp = reinterpret_cast<float4*>(qn + (size_t)idx * 8);
    qp[0] = make_float4(qv[0], qv[1], qv[2], qv[3]);
    qp[1] = make_float4(qv[4], qv[5], qv[6], qv[7]);
    float4* kp = reinterpret_cast<float4*>(kn + (size_t)idx * 8);
    kp[0] = make_float4(kv[0], kv[1], kv[2], kv[3]);
    kp[1] = make_float4(kv[4], kv[5], kv[6], kv[7]);
}

// ---------------------------------------------------------------------------
// Kernel 2: pairwise geometric product, 4 t-values per thread.
// Plain (cached) float4 stores — L2 write-combines partial lines.
// grid = (1, S, B), block = 256; thread covers t = tid*4 .. tid*4+3.
// ---------------------------------------------------------------------------
__device__ __forceinline__ void geom_product(
    float q0, float q1, float q2, float q3, float q4, float q5, float q6, float q7,
    const float4* __restrict__ kp, float4* __restrict__ op)
{
    float4 ka = kp[0], kb4 = kp[1];
    float k0 = ka.x, k1 = ka.y, k2 = ka.z, k3 = ka.w;
    float k4 = kb4.x, k5 = kb4.y, k6 = kb4.z, k7 = kb4.w;

    float o0 = q0*k0 + q1*k1 + q2*k2 + q3*k3 - q4*k4 - q5*k5 - q6*k6 - q7*k7;
    float o1 = q0*k1 + q1*k0 - q2*k4 - q3*k5 + q4*k2 + q5*k3 - q6*k7 - q7*k6;
    float o2 = q0*k2 + q1*k4 + q2*k0 - q3*k6 - q4*k1 + q5*k7 + q6*k3 + q7*k5;
    float o3 = q0*k3 + q1*k5 + q2*k6 + q3*k0 - q4*k7 - q5*k1 - q6*k2 - q7*k4;
    float o4 = q0*k4 + q1*k2 - q2*k1 + q3*k7 + q4*k0 - q5*k6 + q6*k5 + q7*k3;
    float o5 = q0*k5 + q1*k3 - q2*k7 - q3*k1 + q4*k6 + q5*k0 - q6*k4 - q7*k2;
    float o6 = q0*k6 + q1*k7 + q2*k3 - q3*k2 - q4*k5 + q5*k4 + q6*k0 + q7*k1;
    float o7 = q0*k7 + q1*k6 - q2*k5 + q3*k4 + q4*k3 - q5*k2 + q6*k1 + q7*k0;

    op[0] = make_float4(o0, o1, o2, o3);
    op[1] = make_float4(o4, o5, o6, o7);
}

__global__ void __launch_bounds__(256) geomprod_kernel(
    const float* __restrict__ qn,      // (B,S,8)
    const float* __restrict__ kn,      // (B,S,8)
    float* __restrict__ out)           // (B,S,S,8)
{
    int t0 = threadIdx.x * 4;          // this thread does t0 .. t0+3
    int s = blockIdx.y;
    int b = blockIdx.z;

    const float4* qp = reinterpret_cast<const float4*>(qn + ((size_t)b * S + s) * 8);
    float4 qa = qp[0], qb4 = qp[1];
    float q0 = qa.x, q1 = qa.y, q2 = qa.z, q3 = qa.w;
    float q4 = qb4.x, q5 = qb4.y, q6 = qb4.z, q7 = qb4.w;

    const float4* kp = reinterpret_cast<const float4*>(kn + ((size_t)b * S + t0) * 8);
    float4* op = reinterpret_cast<float4*>(out + (((size_t)b * S + s) * S + t0) * 8);

#pragma unroll
    for (int u = 0; u < 4; ++u) {
        geom_product(q0, q1, q2, q3, q4, q5, q6, q7, kp + 2 * u, op + 2 * u);
    }
}

extern "C" void kernel_launch(void* const* d_in, const int* in_sizes, int n_in,
                              void* d_out, int out_size, void* d_ws, size_t ws_size,
                              hipStream_t stream) {
    const float* x  = (const float*)d_in[0];
    const float* qw = (const float*)d_in[1];
    const float* qb = (const float*)d_in[2];
    const float* kw = (const float*)d_in[3];
    const float* kb = (const float*)d_in[4];
    const float* an = (const float*)d_in[5];
    float* out = (float*)d_out;

    float* qn = (float*)d_ws;                       // B*S*8 floats = 256 KB
    float* kn = qn + (size_t)B * S * 8;             // next 256 KB

    int prep_threads = B * S;                        // 8192
    prep_qk_kernel<<<(prep_threads + 255) / 256, 256, 0, stream>>>(
        x, qw, qb, kw, kb, an, qn, kn);

    dim3 grid(1, S, B);                              // 4 t per thread
    geomprod_kernel<<<grid, 256, 0, stream>>>(qn, kn, out);
}

// Round 5
// 60.297 us; speedup vs baseline: 3.4104x; 1.7246x over previous
//
#include <hip/hip_runtime.h>
#include <math.h>

#define DIM 8
constexpr int B = 8;
constexpr int S = 1024;

// ---------------------------------------------------------------------------
// Kernel 1: q/k projection + grade-wise normalization.
// One thread per (b,s) token. 8192 threads total.
// ---------------------------------------------------------------------------
__global__ void __launch_bounds__(256) prep_qk_kernel(
    const float* __restrict__ x,       // (B,S,8)
    const float* __restrict__ qw,      // (8,8) row = d, col = i
    const float* __restrict__ qb,      // (1,)
    const float* __restrict__ kw,      // (8,8)
    const float* __restrict__ kb,      // (1,)
    const float* __restrict__ an,      // (3000,4)
    float* __restrict__ qn,            // (B,S,8)
    float* __restrict__ kn)            // (B,S,8)
{
    int idx = blockIdx.x * blockDim.x + threadIdx.x;   // b*S + s
    if (idx >= B * S) return;
    int s = idx & (S - 1);

    const float4* xp = reinterpret_cast<const float4*>(x + (size_t)idx * 8);
    float4 xa = xp[0], xb = xp[1];
    float xv[8] = {xa.x, xa.y, xa.z, xa.w, xb.x, xb.y, xb.z, xb.w};

    float sa[4];
#pragma unroll
    for (int g = 0; g < 4; ++g) {
        float a = an[s * 4 + g];
        sa[g] = 1.0f / (1.0f + expf(-a));
    }

    float qv[8], kv[8];
#pragma unroll
    for (int i = 0; i < 8; ++i) {
        float accq = (i == 0) ? qb[0] : 0.0f;
        float acck = (i == 0) ? kb[0] : 0.0f;
#pragma unroll
        for (int d = 0; d < 8; ++d) {
            accq += xv[d] * qw[d * 8 + i];
            acck += xv[d] * kw[d * 8 + i];
        }
        qv[i] = accq;
        kv[i] = acck;
    }

    {
        float n0 = sqrtf(qv[0] * qv[0]);
        float n1 = sqrtf(qv[1] * qv[1] + qv[2] * qv[2] + qv[3] * qv[3]);
        float n2 = sqrtf(qv[4] * qv[4] + qv[5] * qv[5] + qv[6] * qv[6]);
        float n3 = sqrtf(qv[7] * qv[7]);
        float d0 = sa[0] * (n0 - 1.0f) + 1.0f + 1e-6f;
        float d1 = sa[1] * (n1 - 1.0f) + 1.0f + 1e-6f;
        float d2 = sa[2] * (n2 - 1.0f) + 1.0f + 1e-6f;
        float d3 = sa[3] * (n3 - 1.0f) + 1.0f + 1e-6f;
        qv[0] /= d0;
        qv[1] /= d1; qv[2] /= d1; qv[3] /= d1;
        qv[4] /= d2; qv[5] /= d2; qv[6] /= d2;
        qv[7] /= d3;
    }
    {
        float n0 = sqrtf(kv[0] * kv[0]);
        float n1 = sqrtf(kv[1] * kv[1] + kv[2] * kv[2] + kv[3] * kv[3]);
        float n2 = sqrtf(kv[4] * kv[4] + kv[5] * kv[5] + kv[6] * kv[6]);
        float n3 = sqrtf(kv[7] * kv[7]);
        float d0 = sa[0] * (n0 - 1.0f) + 1.0f + 1e-6f;
        float d1 = sa[1] * (n1 - 1.0f) + 1.0f + 1e-6f;
        float d2 = sa[2] * (n2 - 1.0f) + 1.0f + 1e-6f;
        float d3 = sa[3] * (n3 - 1.0f) + 1.0f + 1e-6f;
        kv[0] /= d0;
        kv[1] /= d1; kv[2] /= d1; kv[3] /= d1;
        kv[4] /= d2; kv[5] /= d2; kv[6] /= d2;
        kv[7] /= d3;
    }

    float4* qp = reinterpret_cast<float4*>(qn + (size_t)idx * 8);
    qp[0] = make_float4(qv[0], qv[1], qv[2], qv[3]);
    qp[1] = make_float4(qv[4], qv[5], qv[6], qv[7]);
    float4* kp = reinterpret_cast<float4*>(kn + (size_t)idx * 8);
    kp[0] = make_float4(kv[0], kv[1], kv[2], kv[3]);
    kp[1] = make_float4(kv[4], kv[5], kv[6], kv[7]);
}

// ---------------------------------------------------------------------------
// Kernel 2: pairwise geometric product with fully-coalesced stores.
// Block covers t in [t0, t0+256) for one (b,s). Thread tid computes the full
// product for t_a = t0 + tid/2 and t_b = t_a + 128, and stores half h = tid&1
// of each, so each wave's store instruction writes 1 KB contiguous
// (every 64B line fully covered within one instruction).
// grid = (4, S, B), block = 256.
// ---------------------------------------------------------------------------
__device__ __forceinline__ float4 geom_half(
    float q0, float q1, float q2, float q3, float q4, float q5, float q6, float q7,
    const float4* __restrict__ kp, int h)
{
    float4 ka = kp[0], kb4 = kp[1];
    float k0 = ka.x, k1 = ka.y, k2 = ka.z, k3 = ka.w;
    float k4 = kb4.x, k5 = kb4.y, k6 = kb4.z, k7 = kb4.w;

    float o0 = q0*k0 + q1*k1 + q2*k2 + q3*k3 - q4*k4 - q5*k5 - q6*k6 - q7*k7;
    float o1 = q0*k1 + q1*k0 - q2*k4 - q3*k5 + q4*k2 + q5*k3 - q6*k7 - q7*k6;
    float o2 = q0*k2 + q1*k4 + q2*k0 - q3*k6 - q4*k1 + q5*k7 + q6*k3 + q7*k5;
    float o3 = q0*k3 + q1*k5 + q2*k6 + q3*k0 - q4*k7 - q5*k1 - q6*k2 - q7*k4;
    float o4 = q0*k4 + q1*k2 - q2*k1 + q3*k7 + q4*k0 - q5*k6 + q6*k5 + q7*k3;
    float o5 = q0*k5 + q1*k3 - q2*k7 - q3*k1 + q4*k6 + q5*k0 - q6*k4 - q7*k2;
    float o6 = q0*k6 + q1*k7 + q2*k3 - q3*k2 - q4*k5 + q5*k4 + q6*k0 + q7*k1;
    float o7 = q0*k7 + q1*k6 - q2*k5 + q3*k4 + q4*k3 - q5*k2 + q6*k1 + q7*k0;

    return h ? make_float4(o4, o5, o6, o7) : make_float4(o0, o1, o2, o3);
}

__global__ void __launch_bounds__(256) geomprod_kernel(
    const float* __restrict__ qn,      // (B,S,8)
    const float* __restrict__ kn,      // (B,S,8)
    float* __restrict__ out)           // (B,S,S,8)
{
    int tid = threadIdx.x;
    int t0 = blockIdx.x * 256;
    int s = blockIdx.y;
    int b = blockIdx.z;

    int ta = t0 + (tid >> 1);
    int h  = tid & 1;

    const float4* qp = reinterpret_cast<const float4*>(qn + ((size_t)b * S + s) * 8);
    float4 qa = qp[0], qb4 = qp[1];
    float q0 = qa.x, q1 = qa.y, q2 = qa.z, q3 = qa.w;
    float q4 = qb4.x, q5 = qb4.y, q6 = qb4.z, q7 = qb4.w;

    const float4* kpa = reinterpret_cast<const float4*>(kn + ((size_t)b * S + ta) * 8);
    const float4* kpb = kpa + 2 * 128;   // t_b = t_a + 128

    float4 va = geom_half(q0, q1, q2, q3, q4, q5, q6, q7, kpa, h);
    float4 vb = geom_half(q0, q1, q2, q3, q4, q5, q6, q7, kpb, h);

    // element offset t0*8 + tid*4 == (t0 + tid/2)*8 + (tid&1)*4
    float4* op = reinterpret_cast<float4*>(out + (((size_t)b * S + s) * S + t0) * 8);
    op[tid]       = va;   // covers t in [t0,      t0+128)
    op[256 + tid] = vb;   // covers t in [t0+128,  t0+256)
}

extern "C" void kernel_launch(void* const* d_in, const int* in_sizes, int n_in,
                              void* d_out, int out_size, void* d_ws, size_t ws_size,
                              hipStream_t stream) {
    const float* x  = (const float*)d_in[0];
    const float* qw = (const float*)d_in[1];
    const float* qb = (const float*)d_in[2];
    const float* kw = (const float*)d_in[3];
    const float* kb = (const float*)d_in[4];
    const float* an = (const float*)d_in[5];
    float* out = (float*)d_out;

    float* qn = (float*)d_ws;                       // B*S*8 floats = 256 KB
    float* kn = qn + (size_t)B * S * 8;             // next 256 KB

    int prep_threads = B * S;                        // 8192
    prep_qk_kernel<<<(prep_threads + 255) / 256, 256, 0, stream>>>(
        x, qw, qb, kw, kb, an, qn, kn);

    dim3 grid(S / 256, S, B);
    geomprod_kernel<<<grid, 256, 0, stream>>>(qn, kn, out);
}

// Round 6
// 54.655 us; speedup vs baseline: 3.7624x; 1.1032x over previous
//
#include <hip/hip_runtime.h>
#include <math.h>

#define DIM 8
constexpr int B = 8;
constexpr int S = 1024;

// ---------------------------------------------------------------------------
// Kernel 1: q/k projection + grade-wise normalization.
// One thread per (b,s) token. 8192 threads total.
// ---------------------------------------------------------------------------
__global__ void __launch_bounds__(256) prep_qk_kernel(
    const float* __restrict__ x,       // (B,S,8)
    const float* __restrict__ qw,      // (8,8) row = d, col = i
    const float* __restrict__ qb,      // (1,)
    const float* __restrict__ kw,      // (8,8)
    const float* __restrict__ kb,      // (1,)
    const float* __restrict__ an,      // (3000,4)
    float* __restrict__ qn,            // (B,S,8)
    float* __restrict__ kn)            // (B,S,8)
{
    int idx = blockIdx.x * blockDim.x + threadIdx.x;   // b*S + s
    if (idx >= B * S) return;
    int s = idx & (S - 1);

    const float4* xp = reinterpret_cast<const float4*>(x + (size_t)idx * 8);
    float4 xa = xp[0], xb = xp[1];
    float xv[8] = {xa.x, xa.y, xa.z, xa.w, xb.x, xb.y, xb.z, xb.w};

    float sa[4];
#pragma unroll
    for (int g = 0; g < 4; ++g) {
        float a = an[s * 4 + g];
        sa[g] = 1.0f / (1.0f + expf(-a));
    }

    float qv[8], kv[8];
#pragma unroll
    for (int i = 0; i < 8; ++i) {
        float accq = (i == 0) ? qb[0] : 0.0f;
        float acck = (i == 0) ? kb[0] : 0.0f;
#pragma unroll
        for (int d = 0; d < 8; ++d) {
            accq += xv[d] * qw[d * 8 + i];
            acck += xv[d] * kw[d * 8 + i];
        }
        qv[i] = accq;
        kv[i] = acck;
    }

    {
        float n0 = sqrtf(qv[0] * qv[0]);
        float n1 = sqrtf(qv[1] * qv[1] + qv[2] * qv[2] + qv[3] * qv[3]);
        float n2 = sqrtf(qv[4] * qv[4] + qv[5] * qv[5] + qv[6] * qv[6]);
        float n3 = sqrtf(qv[7] * qv[7]);
        float d0 = sa[0] * (n0 - 1.0f) + 1.0f + 1e-6f;
        float d1 = sa[1] * (n1 - 1.0f) + 1.0f + 1e-6f;
        float d2 = sa[2] * (n2 - 1.0f) + 1.0f + 1e-6f;
        float d3 = sa[3] * (n3 - 1.0f) + 1.0f + 1e-6f;
        qv[0] /= d0;
        qv[1] /= d1; qv[2] /= d1; qv[3] /= d1;
        qv[4] /= d2; qv[5] /= d2; qv[6] /= d2;
        qv[7] /= d3;
    }
    {
        float n0 = sqrtf(kv[0] * kv[0]);
        float n1 = sqrtf(kv[1] * kv[1] + kv[2] * kv[2] + kv[3] * kv[3]);
        float n2 = sqrtf(kv[4] * kv[4] + kv[5] * kv[5] + kv[6] * kv[6]);
        float n3 = sqrtf(kv[7] * kv[7]);
        float d0 = sa[0] * (n0 - 1.0f) + 1.0f + 1e-6f;
        float d1 = sa[1] * (n1 - 1.0f) + 1.0f + 1e-6f;
        float d2 = sa[2] * (n2 - 1.0f) + 1.0f + 1e-6f;
        float d3 = sa[3] * (n3 - 1.0f) + 1.0f + 1e-6f;
        kv[0] /= d0;
        kv[1] /= d1; kv[2] /= d1; kv[3] /= d1;
        kv[4] /= d2; kv[5] /= d2; kv[6] /= d2;
        kv[7] /= d3;
    }

    float4* qp = reinterpret_cast<float4*>(qn + (size_t)idx * 8);
    qp[0] = make_float4(qv[0], qv[1], qv[2], qv[3]);
    qp[1] = make_float4(qv[4], qv[5], qv[6], qv[7]);
    float4* kp = reinterpret_cast<float4*>(kn + (size_t)idx * 8);
    kp[0] = make_float4(kv[0], kv[1], kv[2], kv[3]);
    kp[1] = make_float4(kv[4], kv[5], kv[6], kv[7]);
}

// ---------------------------------------------------------------------------
// Kernel 2: pairwise geometric product, one wave per (b,s) output row.
// 8192 waves = 2048 blocks x 4 waves (32 waves/CU). q held in registers;
// 16-iteration t-loop (t = it*64 + lane), unroll x4 so 4 k-loads stay in
// flight and stores issue back-to-back. Plain cached stores.
// ---------------------------------------------------------------------------
__global__ void __launch_bounds__(256) geomprod_kernel(
    const float* __restrict__ qn,      // (B,S,8)
    const float* __restrict__ kn,      // (B,S,8)
    float* __restrict__ out)           // (B,S,S,8)
{
    int wave = blockIdx.x * 4 + (threadIdx.x >> 6);   // 0 .. B*S-1
    int lane = threadIdx.x & 63;
    int b = wave >> 10;                                // wave / S
    int s = wave & (S - 1);

    const float4* qp = reinterpret_cast<const float4*>(qn + ((size_t)b * S + s) * 8);
    float4 qa = qp[0], qb4 = qp[1];
    float q0 = qa.x, q1 = qa.y, q2 = qa.z, q3 = qa.w;
    float q4 = qb4.x, q5 = qb4.y, q6 = qb4.z, q7 = qb4.w;

    const float4* kbase = reinterpret_cast<const float4*>(kn + (size_t)b * S * 8);
    float4* obase = reinterpret_cast<float4*>(out + (((size_t)b * S + s) * S) * 8);

#pragma unroll 4
    for (int it = 0; it < 16; ++it) {
        int t = it * 64 + lane;
        const float4* kp = kbase + 2 * (size_t)t;
        float4 ka = kp[0], kb4 = kp[1];
        float k0 = ka.x, k1 = ka.y, k2 = ka.z, k3 = ka.w;
        float k4 = kb4.x, k5 = kb4.y, k6 = kb4.z, k7 = kb4.w;

        float o0 = q0*k0 + q1*k1 + q2*k2 + q3*k3 - q4*k4 - q5*k5 - q6*k6 - q7*k7;
        float o1 = q0*k1 + q1*k0 - q2*k4 - q3*k5 + q4*k2 + q5*k3 - q6*k7 - q7*k6;
        float o2 = q0*k2 + q1*k4 + q2*k0 - q3*k6 - q4*k1 + q5*k7 + q6*k3 + q7*k5;
        float o3 = q0*k3 + q1*k5 + q2*k6 + q3*k0 - q4*k7 - q5*k1 - q6*k2 - q7*k4;
        float o4 = q0*k4 + q1*k2 - q2*k1 + q3*k7 + q4*k0 - q5*k6 + q6*k5 + q7*k3;
        float o5 = q0*k5 + q1*k3 - q2*k7 - q3*k1 + q4*k6 + q5*k0 - q6*k4 - q7*k2;
        float o6 = q0*k6 + q1*k7 + q2*k3 - q3*k2 - q4*k5 + q5*k4 + q6*k0 + q7*k1;
        float o7 = q0*k7 + q1*k6 - q2*k5 + q3*k4 + q4*k3 - q5*k2 + q6*k1 + q7*k0;

        float4* op = obase + 2 * (size_t)t;
        op[0] = make_float4(o0, o1, o2, o3);
        op[1] = make_float4(o4, o5, o6, o7);
    }
}

extern "C" void kernel_launch(void* const* d_in, const int* in_sizes, int n_in,
                              void* d_out, int out_size, void* d_ws, size_t ws_size,
                              hipStream_t stream) {
    const float* x  = (const float*)d_in[0];
    const float* qw = (const float*)d_in[1];
    const float* qb = (const float*)d_in[2];
    const float* kw = (const float*)d_in[3];
    const float* kb = (const float*)d_in[4];
    const float* an = (const float*)d_in[5];
    float* out = (float*)d_out;

    float* qn = (float*)d_ws;                       // B*S*8 floats = 256 KB
    float* kn = qn + (size_t)B * S * 8;             // next 256 KB

    int prep_threads = B * S;                        // 8192
    prep_qk_kernel<<<(prep_threads + 255) / 256, 256, 0, stream>>>(
        x, qw, qb, kw, kb, an, qn, kn);

    int nblocks = (B * S) / 4;                       // one wave per (b,s) row
    geomprod_kernel<<<nblocks, 256, 0, stream>>>(qn, kn, out);
}